// Round 2
// 991.364 us; speedup vs baseline: 1.0705x; 1.0705x over previous
//
#include <hip/hip_runtime.h>

// LinearAttention on MI355X.
// Pipeline: detect mask layout -> cvt fp32->bf16 (WEIGHTS ONLY) ->
// 3x proj GEMM (fp32 A fused-converted in staging, bf16 MFMA,
// epilogue: elu+1 / mask / q-column sum-of-squares) -> kv outer-product accum
// (register-tiled, k row-normalized in staging) -> kv_reduce (+q-col-norm fold)
// -> fold kv' into Wo (Mt per batch) -> final GEMM.
// R1 change: cvt3 eliminated (fp32->bf16 fused into GEMM A-staging, bit-identical
// RNE pack); XCD-band swizzle on all GEMMs (each XCD owns 32 contiguous row-tiles,
// walks the 8 column-tiles fastest -> A-panel L2 reuse instead of 8x LLC refetch).
// R2: resubmit of R1 (container-level infra failure, no kernel verdict).

typedef unsigned short u16;
typedef __attribute__((ext_vector_type(8))) short short8;
typedef __attribute__((ext_vector_type(4))) float f32x4;

#define GAS __attribute__((address_space(1)))
#define LAS __attribute__((address_space(3)))

__device__ __forceinline__ u16 f2bf(float x) {
  unsigned u = __float_as_uint(x);
  u += 0x7fffu + ((u >> 16) & 1u);   // round-to-nearest-even
  return (u16)(u >> 16);
}
__device__ __forceinline__ unsigned pack2(float a, float b) {
  return (unsigned)f2bf(a) | ((unsigned)f2bf(b) << 16);
}
__device__ __forceinline__ float bflo(unsigned w) { return __uint_as_float(w << 16); }
__device__ __forceinline__ float bfhi(unsigned w) { return __uint_as_float(w & 0xffff0000u); }

// ---------------- mask layout detection (bool bytes vs int32 vs float32) ----------------
__global__ __launch_bounds__(256) void detect_mask(const unsigned* __restrict__ m,
                                                   int* __restrict__ flags) {
  int i = blockIdx.x * 256 + threadIdx.x;          // 8192 words = first 32768 bytes (safe for all layouts)
  unsigned w = m[i];
  if (w & 0xFEFEFEFEu) atomicOr(&flags[1], 1);     // some byte > 1  -> float32 storage
  if (w & 0xFFFFFF00u) atomicOr(&flags[0], 1);     // high bytes set -> 1-byte bool storage
}

__global__ __launch_bounds__(256) void mask_cvt(const void* __restrict__ m,
                                                const int* __restrict__ flags,
                                                float* __restrict__ keep) {
  int i = blockIdx.x * 256 + threadIdx.x;          // 32768 mask entries
  bool pad;
  if (flags[1])      pad = ((const float*)m)[i] != 0.f;
  else if (flags[0]) pad = ((const unsigned char*)m)[i] != 0;
  else               pad = ((const int*)m)[i] != 0;
  keep[i] = pad ? 0.f : 1.f;                        // mask true => zero the key row
}

// ---------------- fp32 -> bf16 conversion (weights only, 4-way merged) ----------------
__device__ __forceinline__ void cvt_body(const float* __restrict__ src,
                                         u16* __restrict__ dst, int n4) {
  int i = blockIdx.x * blockDim.x + threadIdx.x;
  int stride = gridDim.x * blockDim.x;
  for (; i < n4; i += stride) {
    float4 v = ((const float4*)src)[i];
    ((uint2*)dst)[i] = make_uint2(pack2(v.x, v.y), pack2(v.z, v.w));
  }
}
__global__ __launch_bounds__(256) void cvt4(const float* __restrict__ s0, const float* __restrict__ s1,
                                            const float* __restrict__ s2, const float* __restrict__ s3,
                                            u16* __restrict__ d0, u16* __restrict__ d1,
                                            u16* __restrict__ d2, u16* __restrict__ d3, int n4) {
  const float* s = (blockIdx.z == 0) ? s0 : (blockIdx.z == 1) ? s1 : (blockIdx.z == 2) ? s2 : s3;
  u16* d = (blockIdx.z == 0) ? d0 : (blockIdx.z == 1) ? d1 : (blockIdx.z == 2) ? d2 : d3;
  cvt_body(s, d, n4);
}

// ---------------- bt-GEMM: C(M,1024) = A(M,1024) * Bt(1024,1024)^T ----------------
// m97 structure: 128x128 tile, BK=64, 4 waves (2x2), 4x4 16x16x32 bf16 MFMA per wave.
// MODE: 0=Q (fp32 A; elu1 + column sum-of-squares atomics), 1=K (fp32 A; elu1 * keep),
//       2=V (fp32 A; bias only), 3=FINAL (bf16 A; per-batch Bt, fp32 output).
// MODE<3: A is fp32, converted to bf16 (identical RNE) during reg-staging into LDS.
template <int MODE>
__global__ __launch_bounds__(256) void gemm_bt(const void* __restrict__ Ain,
                                               const u16* __restrict__ B0,
                                               const float* __restrict__ bias,
                                               void* __restrict__ Out,
                                               float* __restrict__ sacc,
                                               const float* __restrict__ keep) {
  constexpr int K = 1024;
  __shared__ __align__(16) u16 As[128 * 64];
  __shared__ __align__(16) u16 Bs[128 * 64];

  const int t = threadIdx.x;
  const int w = t >> 6, l = t & 63;
  const int wm = w & 1, wn = w >> 1;               // wave quadrant (rows, cols)

  // XCD-band swizzle: linear block id -> (rowT, colT) so that XCD c (= lin%8,
  // round-robin dispatch assumption) owns row-tiles [c*32, c*32+32) and walks
  // the 8 column-tiles fastest. A-panel (re-read by all 8 col-tiles) then hits
  // the XCD-local L2 instead of being refetched 8x from LLC. Bijective: 2048 blocks.
  const int lin = blockIdx.y * 8 + blockIdx.x;
  const int xcd = lin & 7;
  const int j   = lin >> 3;                        // 0..255
  const int rowTile = (xcd * 32 + (j >> 3)) * 128;
  const int colTile = (j & 7) * 128;
  const int bidx = rowTile >> 12;                  // batch = rowTile/4096

  const u16* B = (MODE == 3) ? (B0 + ((size_t)bidx << 20)) : B0;

  f32x4 acc[4][4] = {};

  const int lr = l >> 3;                           // row within 8-row segment
  const int le = (l & 7) << 3;                     // k-offset in elements (8 elems per lane)
  const float* aRowF = (const float*)Ain + (size_t)(rowTile + w * 32 + lr) * K + le;
  const u16*   aRowB = (const u16*)Ain   + (size_t)(rowTile + w * 32 + lr) * K + le;
  const u16*   bRow  = B + (size_t)(colTile + w * 32 + lr) * K + le;

  for (int kt = 0; kt < K / 64; ++kt) {
    const int k0 = kt * 64;
    __syncthreads();                                // previous iter's LDS reads done
    if constexpr (MODE < 3) {
      // A: fp32 global -> regs -> bf16 (RNE, identical to old cvt3) -> LDS.
      // Same linear LDS layout the global_load_lds path produced.
      float4 r[8];
#pragma unroll
      for (int s = 0; s < 4; ++s) {                 // issue all 8 loads first
        const float* p = aRowF + (size_t)s * 8 * K + k0;
        r[2 * s + 0] = *(const float4*)(p);
        r[2 * s + 1] = *(const float4*)(p + 4);
      }
#pragma unroll
      for (int s = 0; s < 4; ++s) {                 // B gload_lds flies during cvt
        __builtin_amdgcn_global_load_lds((const GAS void*)(bRow + (size_t)s * 8 * K + k0),
                                         (LAS void*)&Bs[(w * 4 + s) * 512], 16, 0, 0);
      }
#pragma unroll
      for (int s = 0; s < 4; ++s) {
        uint4 o;
        o.x = pack2(r[2 * s + 0].x, r[2 * s + 0].y);
        o.y = pack2(r[2 * s + 0].z, r[2 * s + 0].w);
        o.z = pack2(r[2 * s + 1].x, r[2 * s + 1].y);
        o.w = pack2(r[2 * s + 1].z, r[2 * s + 1].w);
        *(uint4*)&As[(w * 4 + s) * 512 + l * 8] = o;
      }
    } else {
#pragma unroll
      for (int s = 0; s < 4; ++s) {                 // wave-uniform LDS base + lane*16
        __builtin_amdgcn_global_load_lds((const GAS void*)(aRowB + (size_t)s * 8 * K + k0),
                                         (LAS void*)&As[(w * 4 + s) * 512], 16, 0, 0);
        __builtin_amdgcn_global_load_lds((const GAS void*)(bRow + (size_t)s * 8 * K + k0),
                                         (LAS void*)&Bs[(w * 4 + s) * 512], 16, 0, 0);
      }
    }
    __syncthreads();                                // staging complete (vmcnt drain)
#pragma unroll
    for (int kk = 0; kk < 2; ++kk) {
      short8 af[4], bf[4];
      const int ko = kk * 32 + ((l >> 4) << 3);     // k = quad*8 + j
#pragma unroll
      for (int mb = 0; mb < 4; ++mb)
        af[mb] = *(const short8*)&As[(wm * 64 + mb * 16 + (l & 15)) * 64 + ko];
#pragma unroll
      for (int nb = 0; nb < 4; ++nb)
        bf[nb] = *(const short8*)&Bs[(wn * 64 + nb * 16 + (l & 15)) * 64 + ko];
#pragma unroll
      for (int mb = 0; mb < 4; ++mb)
#pragma unroll
        for (int nb = 0; nb < 4; ++nb)
          acc[mb][nb] = __builtin_amdgcn_mfma_f32_16x16x32_bf16(af[mb], bf[nb], acc[mb][nb], 0, 0, 0);
    }
  }

  // Epilogue. C/D layout: col = lane&15, row = (lane>>4)*4 + reg (verified m89/m91).
  const int qr = (l >> 4) << 2;
  const int cl = l & 15;
#pragma unroll
  for (int nb = 0; nb < 4; ++nb) {
    const int col = colTile + wn * 64 + nb * 16 + cl;
    const float bv = bias[col];
    float csum = 0.f;
#pragma unroll
    for (int mb = 0; mb < 4; ++mb) {
      const int rowb = rowTile + wm * 64 + mb * 16 + qr;
#pragma unroll
      for (int r = 0; r < 4; ++r) {
        float y = acc[mb][nb][r] + bv;
        if (MODE == 0 || MODE == 1) y = (y > 0.f) ? (y + 1.f) : __expf(y);  // 1+elu
        if (MODE == 1) y *= keep[rowb + r];
        if (MODE == 3) ((float*)Out)[(size_t)(rowb + r) * 1024 + col] = y;
        else           ((u16*)Out)[(size_t)(rowb + r) * 1024 + col] = f2bf(y);
        if (MODE == 0) csum += y * y;
      }
    }
    if (MODE == 0) {
      csum += __shfl_xor(csum, 16);
      csum += __shfl_xor(csum, 32);
      if (l < 16) atomicAdd(&sacc[bidx * 1024 + colTile + wn * 64 + nb * 16 + l], csum);
    }
  }
}

// ---------------- kv outer-product: kvpart[ch][b,h] = sum_i (k_i/||k_i||) x v_i ----------------
// 512 blocks (4 chunks x 16 h x 8 b), 256 thr. Each wave = one i-group; lane owns 8x8 (d,e).
__global__ __launch_bounds__(256, 2) void kv2(const u16* __restrict__ fk,
                                              const u16* __restrict__ fv,
                                              float* __restrict__ kvpart) {
  const int ch = blockIdx.x, h = blockIdx.y, b = blockIdx.z;
  __shared__ __align__(16) u16 smem[2 * 256 * 64];   // 64 KB (reused as reduce scratch)
  u16* lk = smem;
  u16* lv = smem + 256 * 64;
  const int t = threadIdx.x;
  const int w = t >> 6, l = t & 63;
  const int d8 = (l & 7) * 8, e8 = (l >> 3) * 8;
  float acc[64] = {};

  for (int sub = 0; sub < 4; ++sub) {
    const int i0 = ch * 1024 + sub * 256;
    __syncthreads();                                 // prior phase-2 reads done
    {   // phase 1: thread t stages row i0+t; k gets 1/||k|| folded in
      const size_t g = ((size_t)(b * 4096 + i0 + t)) * 1024 + h * 64;
      const uint4* kp = (const uint4*)&fk[g];
      float kf[64];
#pragma unroll
      for (int j = 0; j < 8; ++j) {
        uint4 kq = kp[j];
        kf[j * 8 + 0] = bflo(kq.x); kf[j * 8 + 1] = bfhi(kq.x);
        kf[j * 8 + 2] = bflo(kq.y); kf[j * 8 + 3] = bfhi(kq.y);
        kf[j * 8 + 4] = bflo(kq.z); kf[j * 8 + 5] = bfhi(kq.z);
        kf[j * 8 + 6] = bflo(kq.w); kf[j * 8 + 7] = bfhi(kq.w);
      }
      float ss = 0.f;
#pragma unroll
      for (int j = 0; j < 64; ++j) ss += kf[j] * kf[j];
      const float inv = 1.f / fmaxf(sqrtf(ss), 1e-12f);   // masked rows: 0 * big = 0
#pragma unroll
      for (int j = 0; j < 8; ++j) {
        uint4 o;
        o.x = pack2(kf[j * 8 + 0] * inv, kf[j * 8 + 1] * inv);
        o.y = pack2(kf[j * 8 + 2] * inv, kf[j * 8 + 3] * inv);
        o.z = pack2(kf[j * 8 + 4] * inv, kf[j * 8 + 5] * inv);
        o.w = pack2(kf[j * 8 + 6] * inv, kf[j * 8 + 7] * inv);
        *(uint4*)&lk[t * 64 + j * 8] = o;
      }
      const uint4* vp = (const uint4*)&fv[g];
#pragma unroll
      for (int j = 0; j < 8; ++j) *(uint4*)&lv[t * 64 + j * 8] = vp[j];
    }
    __syncthreads();
    // phase 2: wave w reduces i in [w*64, w*64+64)
#pragma unroll 2
    for (int ii = 0; ii < 64; ++ii) {
      const int i = w * 64 + ii;
      uint4 kw4 = *(const uint4*)&lk[i * 64 + d8];   // 8 distinct addrs/wave, 8-way broadcast
      uint4 vw4 = *(const uint4*)&lv[i * 64 + e8];
      float ka[8], va[8];
      ka[0] = bflo(kw4.x); ka[1] = bfhi(kw4.x); ka[2] = bflo(kw4.y); ka[3] = bfhi(kw4.y);
      ka[4] = bflo(kw4.z); ka[5] = bfhi(kw4.z); ka[6] = bflo(kw4.w); ka[7] = bfhi(kw4.w);
      va[0] = bflo(vw4.x); va[1] = bfhi(vw4.x); va[2] = bflo(vw4.y); va[3] = bfhi(vw4.y);
      va[4] = bflo(vw4.z); va[5] = bfhi(vw4.z); va[6] = bflo(vw4.w); va[7] = bfhi(vw4.w);
#pragma unroll
      for (int a = 0; a < 8; ++a)
#pragma unroll
        for (int c = 0; c < 8; ++c)
          acc[a * 8 + c] += ka[a] * va[c];
    }
  }

  // cross-wave reduce in LDS, wave 0 writes the block's partial (no atomics)
  __syncthreads();
  float* scratch = (float*)smem;                      // 48 KB of the 64 KB staging area
  if (w > 0) {
#pragma unroll
    for (int c = 0; c < 64; c += 4)
      *(float4*)&scratch[((w - 1) * 64 + l) * 64 + c] = *(float4*)&acc[c];
  }
  __syncthreads();
  if (w == 0) {
#pragma unroll
    for (int p = 0; p < 3; ++p)
#pragma unroll
      for (int c = 0; c < 64; c += 4) {
        float4 s = *(const float4*)&scratch[(p * 64 + l) * 64 + c];
        acc[c + 0] += s.x; acc[c + 1] += s.y; acc[c + 2] += s.z; acc[c + 3] += s.w;
      }
    float* dst = kvpart + (size_t)(((ch * 8 + b) * 16 + h)) * 4096;
#pragma unroll
    for (int a = 0; a < 8; ++a)
#pragma unroll
      for (int c = 0; c < 8; c += 4)
        *(float4*)&dst[(d8 + a) * 64 + e8 + c] = *(float4*)&acc[a * 8 + c];
  }
}

// ---- kv_reduce: kvred[b,h] = (sum_ch kvpart) row-scaled by 1/max(||q_col||,eps) ----
__global__ __launch_bounds__(256) void kv_reduce(const float* __restrict__ kvpart,
                                                 const float* __restrict__ sacc,
                                                 float* __restrict__ kvred) {
  const int bh = blockIdx.x;                          // b*16+h
  const int b = bh >> 4, h = bh & 15;
  const int t = threadIdx.x;
  const int d = t >> 2;                               // 16 consecutive floats stay in one kv row
  const float invq = 1.f / fmaxf(sqrtf(sacc[b * 1024 + h * 64 + d]), 1e-12f);
#pragma unroll
  for (int j = 0; j < 4; ++j) {
    const size_t off = (size_t)bh * 4096 + t * 16 + j * 4;
    float4 s = *(const float4*)&kvpart[off];
#pragma unroll
    for (int ch = 1; ch < 4; ++ch) {
      float4 p = *(const float4*)&kvpart[(size_t)ch * 524288 + off];
      s.x += p.x; s.y += p.y; s.z += p.z; s.w += p.w;
    }
    s.x *= invq; s.y *= invq; s.z *= invq; s.w *= invq;
    *(float4*)&kvred[(size_t)bh * 4096 + t * 16 + j * 4] = s;
  }
}

// ------- fold: Mt[b][j][64h+d] = sum_e kvred[b,h,d,e] * Wo[j][64h+e] -------
__global__ __launch_bounds__(256) void scale_mt(const float* __restrict__ kvred,
                                                const u16* __restrict__ wob,
                                                u16* __restrict__ Mt) {
  const int jt = blockIdx.x, h = blockIdx.y, b = blockIdx.z;
  __shared__ float kvl[64 * 64];
  const int t = threadIdx.x;

  {  // load kv (already scaled)
    const int d = t >> 2, cp = (t & 3) * 16;
    const float* src = kvred + (size_t)((b * 16 + h) * 4096) + d * 64 + cp;
#pragma unroll
    for (int c = 0; c < 16; c += 4)
      *(float4*)&kvl[d * 64 + cp + c] = *(const float4*)&src[c];
  }
  __syncthreads();

  const int j = jt * 128 + (t & 127);
  const int g = t >> 7;                              // 0..1 -> d 0..31 / 32..63
  float wo[64];
  const u16* wp = wob + (size_t)j * 1024 + h * 64;
#pragma unroll
  for (int e8 = 0; e8 < 64; e8 += 8) {
    uint4 q = *(const uint4*)&wp[e8];
    wo[e8 + 0] = bflo(q.x); wo[e8 + 1] = bfhi(q.x);
    wo[e8 + 2] = bflo(q.y); wo[e8 + 3] = bfhi(q.y);
    wo[e8 + 4] = bflo(q.z); wo[e8 + 5] = bfhi(q.z);
    wo[e8 + 6] = bflo(q.w); wo[e8 + 7] = bfhi(q.w);
  }
  u16* op = Mt + ((size_t)b << 20) + (size_t)j * 1024 + h * 64 + g * 32;
#pragma unroll 4
  for (int dd = 0; dd < 32; ++dd) {
    const int drow = g * 32 + dd;
    float s = 0.f;
#pragma unroll
    for (int e = 0; e < 64; ++e) s += kvl[drow * 64 + e] * wo[e];
    op[dd] = f2bf(s);
  }
}

// ---------------- launcher ----------------
extern "C" void kernel_launch(void* const* d_in, const int* in_sizes, int n_in,
                              void* d_out, int out_size, void* d_ws, size_t ws_size,
                              hipStream_t stream) {
  const float* query = (const float*)d_in[0];
  const float* key   = (const float*)d_in[1];
  const float* value = (const float*)d_in[2];
  const void*  mask  = d_in[3];
  const float* Wq = (const float*)d_in[4];
  const float* bq = (const float*)d_in[5];
  const float* Wk = (const float*)d_in[6];
  const float* bk = (const float*)d_in[7];
  const float* Wv = (const float*)d_in[8];
  const float* bv = (const float*)d_in[9];
  const float* Wo = (const float*)d_in[10];
  const float* bo = (const float*)d_in[11];

  char* W = (char*)d_ws;
  int*   flags = (int*)W;                            // 256 B
  float* sacc  = (float*)(W + 256);                  // 8*1024 f32 = 32 KB
  float* keep  = (float*)(W + 33024);                // 32768 f32 = 128 KB
  u16* wqb = (u16*)(W + 164096);                     // 4 x 2 MB weights
  u16* wkb = wqb + 1048576;
  u16* wvb = wkb + 1048576;
  u16* wob = wvb + 1048576;
  u16* fq  = wob + 1048576;                          // 3 x 64 MB activations (bf16)
  u16* fk  = fq + 33554432;
  u16* fv  = fk + 33554432;
  u16* Mt  = fv + 33554432;                          // 16 MB (8 x 1024x1024 bf16)
  float* kvpart = (float*)(Mt + 8388608);            // 8 MB
  float* kvred  = kvpart + 2097152;                  // 2 MB

  hipMemsetAsync(d_ws, 0, 33024, stream);            // flags + sacc only

  detect_mask<<<32, 256, 0, stream>>>((const unsigned*)mask, flags);
  mask_cvt<<<128, 256, 0, stream>>>(mask, flags, keep);

  cvt4<<<dim3(128, 1, 4), 256, 0, stream>>>(Wq, Wk, Wv, Wo, wqb, wkb, wvb, wob, 262144);

  dim3 gg(8, 256);
  gemm_bt<0><<<gg, 256, 0, stream>>>(query, wqb, bq, fq, sacc, nullptr);
  gemm_bt<1><<<gg, 256, 0, stream>>>(key,   wkb, bk, fk, nullptr, keep);
  gemm_bt<2><<<gg, 256, 0, stream>>>(value, wvb, bv, fv, nullptr, nullptr);

  kv2<<<dim3(4, 16, 8), 256, 0, stream>>>(fk, fv, kvpart);
  kv_reduce<<<128, 256, 0, stream>>>(kvpart, sacc, kvred);
  scale_mt<<<dim3(8, 16, 8), 256, 0, stream>>>(kvred, wob, Mt);

  gemm_bt<3><<<gg, 256, 0, stream>>>(fq, Mt, bo, d_out, nullptr, nullptr);
}